// Round 1
// baseline (288.858 us; speedup 1.0000x reference)
//
#include <hip/hip_runtime.h>

// Problem constants (from reference)
constexpr int BSZ = 32;
constexpr int CH  = 64;
constexpr int HH  = 32;
constexpr int WW  = 128;
constexpr int HW  = HH * WW;   // 4096
constexpr int NP  = 512;
constexpr float EPS = 1e-8f;

__device__ __forceinline__ float tanh_fast(float x) {
    // tanh(x) = 1 - 2/(exp(2x)+1); exact at +-inf, ~1e-7 rel error.
    float e = __expf(2.0f * x);
    return 1.0f - 2.0f * __builtin_amdgcn_rcpf(e + 1.0f);
}

// K1: per position p of batch b, compute
//   e_t = Va_b + sum_o Va_w[o] * tanh( Ua_w[o,:] . key[b,:,p] + Ua_b[o] + query[b,o] )
//   e_exp[b*HW+p] = exp(e_t)
// One thread per position. Weights accessed with wave-uniform indices ->
// compiler scalarizes to s_load; v_fma takes the SGPR operand directly.
__global__ __launch_bounds__(256, 2) void k_scores(
    const float* __restrict__ key,
    const float* __restrict__ query,
    const float* __restrict__ Ua_w,
    const float* __restrict__ Ua_b,
    const float* __restrict__ Va_w,
    const float* __restrict__ Va_b,
    float* __restrict__ e_exp)
{
    const int gid = blockIdx.x * 256 + threadIdx.x;   // 0 .. BSZ*HW-1
    const int b = gid >> 12;          // / 4096 (block-uniform: 4096 % 256 == 0)
    const int p = gid & (HW - 1);

    // Load this position's 64-channel key vector into registers.
    // Stride between channels is HW floats; each instruction is lane-coalesced.
    const float* kb = key + (size_t)b * CH * HW + p;
    float kr[CH];
#pragma unroll
    for (int c = 0; c < CH; ++c) kr[c] = kb[(size_t)c * HW];

    const float* qb = query + b * NP;

    float et = 0.0f;
#pragma unroll 2
    for (int o = 0; o < NP; ++o) {
        const float* wr = Ua_w + o * CH;   // uniform address -> s_load
        float s0 = 0.0f, s1 = 0.0f, s2 = 0.0f, s3 = 0.0f;
#pragma unroll
        for (int c = 0; c < CH; c += 4) {
            s0 = fmaf(wr[c + 0], kr[c + 0], s0);
            s1 = fmaf(wr[c + 1], kr[c + 1], s1);
            s2 = fmaf(wr[c + 2], kr[c + 2], s2);
            s3 = fmaf(wr[c + 3], kr[c + 3], s3);
        }
        float s = ((s0 + s1) + (s2 + s3)) + qb[o] + Ua_b[o];
        et = fmaf(Va_w[o], tanh_fast(s), et);
    }
    e_exp[gid] = __expf(et + Va_b[0]);
}

// K2: per-batch denominator; inv_denom[b] = 1/(sum_p e_exp + EPS)
__global__ __launch_bounds__(256) void k_denom(
    const float* __restrict__ e_exp,
    float* __restrict__ inv_denom)
{
    const int b = blockIdx.x;
    const int tid = threadIdx.x;
    const float4* e4 = (const float4*)(e_exp + b * HW);
    float s = 0.0f;
#pragma unroll
    for (int i = 0; i < HW / 4 / 256; ++i) {
        float4 v = e4[tid + i * 256];
        s += (v.x + v.y) + (v.z + v.w);
    }
    // wave64 reduce
#pragma unroll
    for (int off = 32; off > 0; off >>= 1) s += __shfl_down(s, off, 64);
    __shared__ float wsum[4];
    if ((tid & 63) == 0) wsum[tid >> 6] = s;
    __syncthreads();
    if (tid == 0) {
        float t = (wsum[0] + wsum[1]) + (wsum[2] + wsum[3]);
        inv_denom[b] = 1.0f / (t + EPS);
    }
}

// K3: out[b,c,p] = feature[b,c,p] * e_exp[b,p] * inv_denom[b]  (float4 vectorized)
__global__ __launch_bounds__(256) void k_scale(
    const float* __restrict__ feature,
    const float* __restrict__ e_exp,
    const float* __restrict__ inv_denom,
    float* __restrict__ out)
{
    const int idx = blockIdx.x * 256 + threadIdx.x;   // float4 index
    const int pq = idx & (HW / 4 - 1);                // 0..1023
    const int bc = idx >> 10;                         // 0..BSZ*CH-1
    const int b  = bc >> 6;                           // block-uniform

    const float sc = inv_denom[b];
    const float4 e = ((const float4*)(e_exp + (size_t)b * HW))[pq];
    const float4 f = ((const float4*)feature)[idx];
    float4 o;
    o.x = f.x * (e.x * sc);
    o.y = f.y * (e.y * sc);
    o.z = f.z * (e.z * sc);
    o.w = f.w * (e.w * sc);
    ((float4*)out)[idx] = o;
}

extern "C" void kernel_launch(void* const* d_in, const int* in_sizes, int n_in,
                              void* d_out, int out_size, void* d_ws, size_t ws_size,
                              hipStream_t stream)
{
    const float* feature = (const float*)d_in[0];
    const float* query   = (const float*)d_in[1];
    const float* key     = (const float*)d_in[2];
    const float* Ua_w    = (const float*)d_in[3];
    const float* Ua_b    = (const float*)d_in[4];
    const float* Va_w    = (const float*)d_in[5];
    const float* Va_b    = (const float*)d_in[6];

    float* e_exp     = (float*)d_ws;                  // BSZ*HW floats
    float* inv_denom = e_exp + BSZ * HW;              // BSZ floats

    k_scores<<<BSZ * HW / 256, 256, 0, stream>>>(key, query, Ua_w, Ua_b, Va_w, Va_b, e_exp);
    k_denom<<<BSZ, 256, 0, stream>>>(e_exp, inv_denom);
    k_scale<<<(BSZ * CH * HW / 4) / 256, 256, 0, stream>>>(feature, e_exp, inv_denom, (float*)d_out);
}

// Round 2
// 185.697 us; speedup vs baseline: 1.5555x; 1.5555x over previous
//
#include <hip/hip_runtime.h>

// Problem constants (from reference)
constexpr int BSZ = 32;
constexpr int CH  = 64;
constexpr int HH  = 32;
constexpr int WW  = 128;
constexpr int HW  = HH * WW;   // 4096
constexpr int NP  = 512;
constexpr int OSPLIT = 4;      // o-loop split factor
constexpr int OCHUNK = NP / OSPLIT;  // 128
constexpr float EPS = 1e-8f;

__device__ __forceinline__ float tanh_fast(float x) {
    // tanh(x) = 1 - 2/(exp(2x)+1); exact at +-inf, ~1e-7 rel error.
    float e = __expf(2.0f * x);
    return 1.0f - 2.0f * __builtin_amdgcn_rcpf(e + 1.0f);
}

// K1: partial logits. Block handles 256 positions and OCHUNK of the 512
// output channels:
//   e_part[r][b*HW+p] = sum_{o in chunk r} Va_w[o]*tanh(Ua_w[o,:].key[b,:,p]
//                                                       + Ua_b[o] + query[b,o])
// kr[64] is pinned in VGPRs (asm liveness pin keeps the compiler from sinking
// the loads into the o-loop, which round-1 counters showed it did: VGPR=64).
// Weight/bias/query reads are wave-uniform -> s_load; the FMA takes the SGPR
// operand directly, so the hot loop has zero vector-memory instructions.
__global__ __launch_bounds__(256, 5) void k_scores(
    const float* __restrict__ key,
    const float* __restrict__ query,
    const float* __restrict__ Ua_w,
    const float* __restrict__ Ua_b,
    const float* __restrict__ Va_w,
    float* __restrict__ e_part)
{
    const int pb  = blockIdx.x & (BSZ * HW / 256 - 1);   // position-block 0..511
    const int r   = blockIdx.x >> 9;                     // o-chunk 0..3
    const int gid = pb * 256 + threadIdx.x;              // 0 .. BSZ*HW-1
    const int b   = gid >> 12;                           // block-uniform
    const int p   = gid & (HW - 1);

    const float* kb = key + (size_t)b * CH * HW + p;
    float kr[CH];
#pragma unroll
    for (int c = 0; c < CH; ++c) kr[c] = kb[(size_t)c * HW];
#pragma unroll
    for (int c = 0; c < CH; ++c) asm volatile("" : "+v"(kr[c]));  // pin in VGPRs

    const float* qb = query + b * NP;
    const int o0 = r * OCHUNK;

    float et = 0.0f;
#pragma unroll 2
    for (int oo = 0; oo < OCHUNK; ++oo) {
        const int o = o0 + oo;
        const float* wr = Ua_w + o * CH;     // uniform address -> s_load
        float s0 = 0.0f, s1 = 0.0f, s2 = 0.0f, s3 = 0.0f;
#pragma unroll
        for (int c = 0; c < CH; c += 4) {
            s0 = fmaf(wr[c + 0], kr[c + 0], s0);
            s1 = fmaf(wr[c + 1], kr[c + 1], s1);
            s2 = fmaf(wr[c + 2], kr[c + 2], s2);
            s3 = fmaf(wr[c + 3], kr[c + 3], s3);
        }
        float s = ((s0 + s1) + (s2 + s3)) + qb[o] + Ua_b[o];
        et = fmaf(Va_w[o], tanh_fast(s), et);
    }
    e_part[(size_t)r * (BSZ * HW) + gid] = et;
}

// K2: combine partials, exp, per-batch denominator.
__global__ __launch_bounds__(256) void k_denom(
    const float* __restrict__ e_part,
    const float* __restrict__ Va_b,
    float* __restrict__ e_exp,
    float* __restrict__ inv_denom)
{
    const int b = blockIdx.x;
    const int tid = threadIdx.x;
    const float vb = Va_b[0];
    float s = 0.0f;
#pragma unroll
    for (int i = 0; i < HW / 256; ++i) {
        const int idx = b * HW + i * 256 + tid;
        float et = ((e_part[idx] + e_part[BSZ * HW + idx]) +
                    (e_part[2 * BSZ * HW + idx] + e_part[3 * BSZ * HW + idx])) + vb;
        float e = __expf(et);
        e_exp[idx] = e;
        s += e;
    }
#pragma unroll
    for (int off = 32; off > 0; off >>= 1) s += __shfl_down(s, off, 64);
    __shared__ float wsum[4];
    if ((tid & 63) == 0) wsum[tid >> 6] = s;
    __syncthreads();
    if (tid == 0) {
        float t = (wsum[0] + wsum[1]) + (wsum[2] + wsum[3]);
        inv_denom[b] = 1.0f / (t + EPS);
    }
}

// K3: out[b,c,p] = feature[b,c,p] * e_exp[b,p] * inv_denom[b]  (float4)
__global__ __launch_bounds__(256) void k_scale(
    const float* __restrict__ feature,
    const float* __restrict__ e_exp,
    const float* __restrict__ inv_denom,
    float* __restrict__ out)
{
    const int idx = blockIdx.x * 256 + threadIdx.x;   // float4 index
    const int pq = idx & (HW / 4 - 1);                // 0..1023
    const int bc = idx >> 10;                         // 0..BSZ*CH-1
    const int b  = bc >> 6;                           // block-uniform

    const float sc = inv_denom[b];
    const float4 e = ((const float4*)(e_exp + (size_t)b * HW))[pq];
    const float4 f = ((const float4*)feature)[idx];
    float4 o;
    o.x = f.x * (e.x * sc);
    o.y = f.y * (e.y * sc);
    o.z = f.z * (e.z * sc);
    o.w = f.w * (e.w * sc);
    ((float4*)out)[idx] = o;
}

extern "C" void kernel_launch(void* const* d_in, const int* in_sizes, int n_in,
                              void* d_out, int out_size, void* d_ws, size_t ws_size,
                              hipStream_t stream)
{
    const float* feature = (const float*)d_in[0];
    const float* query   = (const float*)d_in[1];
    const float* key     = (const float*)d_in[2];
    const float* Ua_w    = (const float*)d_in[3];
    const float* Ua_b    = (const float*)d_in[4];
    const float* Va_w    = (const float*)d_in[5];
    const float* Va_b    = (const float*)d_in[6];

    float* e_part    = (float*)d_ws;                       // OSPLIT*BSZ*HW floats
    float* e_exp     = e_part + (size_t)OSPLIT * BSZ * HW; // BSZ*HW floats
    float* inv_denom = e_exp + BSZ * HW;                   // BSZ floats

    k_scores<<<(BSZ * HW / 256) * OSPLIT, 256, 0, stream>>>(
        key, query, Ua_w, Ua_b, Va_w, e_part);
    k_denom<<<BSZ, 256, 0, stream>>>(e_part, Va_b, e_exp, inv_denom);
    k_scale<<<(BSZ * CH * HW / 4) / 256, 256, 0, stream>>>(
        feature, e_exp, inv_denom, (float*)d_out);
}

// Round 3
// 65.049 us; speedup vs baseline: 4.4406x; 2.8547x over previous
//
#include <hip/hip_runtime.h>

typedef unsigned short ushort_t;
typedef unsigned int uint_t;

constexpr int BSZ = 32;
constexpr int CH  = 64;
constexpr int HW  = 32 * 128;   // 4096
constexpr int NP  = 512;
constexpr float EPS = 1e-8f;

using short8 = __attribute__((ext_vector_type(8))) short;   // 8 bf16 (4 VGPRs)
using f32x4  = __attribute__((ext_vector_type(4))) float;

__device__ __forceinline__ ushort_t f2bf(float f) {   // fp32 -> bf16 RNE
    uint_t u = __builtin_bit_cast(uint_t, f);
    u += 0x7FFFu + ((u >> 16) & 1u);
    return (ushort_t)(u >> 16);
}
__device__ __forceinline__ float bf2f(ushort_t b) {
    uint_t u = ((uint_t)b) << 16;
    return __builtin_bit_cast(float, u);
}
__device__ __forceinline__ float tanh_fast(float x) {
    // tanh(x) = 1 - 2/(exp(2x)+1); exact at +-inf, ~1e-7 rel error.
    float e = __expf(x + x);
    float r = __builtin_amdgcn_rcpf(e + 1.0f);
    return fmaf(-2.0f, r, 1.0f);
}

// K0: split W into bf16 hi/lo; fold Ua_b+query into QB.
__global__ __launch_bounds__(256) void k_prep(
    const float* __restrict__ Ua_w, const float* __restrict__ Ua_b,
    const float* __restrict__ query,
    ushort_t* __restrict__ Whi, ushort_t* __restrict__ Wlo,
    float* __restrict__ QB)
{
    const int i = blockIdx.x * 256 + threadIdx.x;
    if (i < NP * CH) {
        float x = Ua_w[i];
        ushort_t h = f2bf(x);
        Whi[i] = h;
        Wlo[i] = f2bf(x - bf2f(h));
    }
    if (i < BSZ * NP) {
        QB[i] = query[i] + Ua_b[i & (NP - 1)];
    }
}

// K1: e_t[b,p] = sum_o Va_w[o] * tanh( W[o,:].key[b,:,p] + QB[b,o] )
// MFMA 16x16x32 bf16, 3-pass split (hi.hi + hi.lo + lo.hi; lo.lo ~2^-18 dropped).
// Block = 4 waves; wave owns 64 positions; key chunk register-cached as B-frags
// (reused across all 32 m-tiles). A-frags (W bf16) stream from L2, L1-broadcast
// across the block's 4 waves.
__global__ __launch_bounds__(256, 2) void k_scores(
    const float* __restrict__ key,
    const ushort_t* __restrict__ Whi, const ushort_t* __restrict__ Wlo,
    const float* __restrict__ QB, const float* __restrict__ Va_w,
    float* __restrict__ e_t)
{
    const int bx = blockIdx.x;
    const int b  = bx >> 4;               // batch
    const int pc = bx & 15;               // 256-position chunk
    const int wv = threadIdx.x >> 6;
    const int l  = threadIdx.x & 63;
    const int lm = l & 15;                // col-in-tile (A row / B,C col)
    const int kg = l >> 4;                // k-group
    const int p0 = pc * 256 + wv * 64;    // wave's first position

    // ---- load + bf16-split this wave's B = key[b, :, p0..p0+63] ----
    // B-frag layout: col = l&15, k = kg*8 + j  (within each K=32 step)
    short8 Bh[4][2], Bl[4][2];
    const float* kb = key + (size_t)b * CH * HW;
#pragma unroll
    for (int nt = 0; nt < 4; ++nt) {
#pragma unroll
        for (int ks = 0; ks < 2; ++ks) {
#pragma unroll
            for (int j = 0; j < 8; ++j) {
                float x = kb[(size_t)(ks * 32 + kg * 8 + j) * HW + (p0 + nt * 16 + lm)];
                ushort_t h = f2bf(x);
                Bh[nt][ks][j] = (short)h;
                Bl[nt][ks][j] = (short)f2bf(x - bf2f(h));
            }
        }
    }

    const float* qbp = QB + b * NP;
    float ew[4] = {0.0f, 0.0f, 0.0f, 0.0f};

#pragma unroll 2
    for (int mt = 0; mt < NP / 16; ++mt) {
        // A-frags: row = l&15, k = kg*8+j, contiguous 8 bf16 -> one dwordx4
        const int arow = (mt * 16 + lm) * CH + kg * 8;
        const short8 Ah0 = *(const short8*)(Whi + arow);
        const short8 Ah1 = *(const short8*)(Whi + arow + 32);
        const short8 Al0 = *(const short8*)(Wlo + arow);
        const short8 Al1 = *(const short8*)(Wlo + arow + 32);

        f32x4 acc[4];
#pragma unroll
        for (int nt = 0; nt < 4; ++nt) acc[nt] = (f32x4){0.f, 0.f, 0.f, 0.f};
#pragma unroll
        for (int nt = 0; nt < 4; ++nt) {
            acc[nt] = __builtin_amdgcn_mfma_f32_16x16x32_bf16(Ah0, Bh[nt][0], acc[nt], 0, 0, 0);
            acc[nt] = __builtin_amdgcn_mfma_f32_16x16x32_bf16(Ah1, Bh[nt][1], acc[nt], 0, 0, 0);
            acc[nt] = __builtin_amdgcn_mfma_f32_16x16x32_bf16(Ah0, Bl[nt][0], acc[nt], 0, 0, 0);
            acc[nt] = __builtin_amdgcn_mfma_f32_16x16x32_bf16(Ah1, Bl[nt][1], acc[nt], 0, 0, 0);
            acc[nt] = __builtin_amdgcn_mfma_f32_16x16x32_bf16(Al0, Bh[nt][0], acc[nt], 0, 0, 0);
            acc[nt] = __builtin_amdgcn_mfma_f32_16x16x32_bf16(Al1, Bh[nt][1], acc[nt], 0, 0, 0);
        }

        // C/D layout: col = l&15, row = kg*4 + r  ->  o = mt*16 + kg*4 + r
        const f32x4 qb = *(const f32x4*)(qbp + mt * 16 + kg * 4);
        const f32x4 vw = *(const f32x4*)(Va_w + mt * 16 + kg * 4);
#pragma unroll
        for (int nt = 0; nt < 4; ++nt) {
#pragma unroll
            for (int r = 0; r < 4; ++r) {
                float s = acc[nt][r] + qb[r];
                ew[nt] = fmaf(vw[r], tanh_fast(s), ew[nt]);
            }
        }
    }

    // reduce over the 4 k-groups (rows live in lanes l, l^16, l^32, l^48)
#pragma unroll
    for (int nt = 0; nt < 4; ++nt) {
        ew[nt] += __shfl_xor(ew[nt], 16, 64);
        ew[nt] += __shfl_xor(ew[nt], 32, 64);
    }
    if (kg == 0) {
#pragma unroll
        for (int nt = 0; nt < 4; ++nt)
            e_t[(size_t)b * HW + p0 + nt * 16 + lm] = ew[nt];
    }
}

// K2: e_exp = exp(e_t + Va_b); inv_denom[b] = 1/(sum + EPS)
__global__ __launch_bounds__(256) void k_denom(
    const float* __restrict__ e_t,
    const float* __restrict__ Va_b,
    float* __restrict__ e_exp,
    float* __restrict__ inv_denom)
{
    const int b = blockIdx.x;
    const int tid = threadIdx.x;
    const float vb = Va_b[0];
    float s = 0.0f;
#pragma unroll
    for (int i = 0; i < HW / 256; ++i) {
        const int idx = b * HW + i * 256 + tid;
        float e = __expf(e_t[idx] + vb);
        e_exp[idx] = e;
        s += e;
    }
#pragma unroll
    for (int off = 32; off > 0; off >>= 1) s += __shfl_down(s, off, 64);
    __shared__ float wsum[4];
    if ((tid & 63) == 0) wsum[tid >> 6] = s;
    __syncthreads();
    if (tid == 0) {
        float t = (wsum[0] + wsum[1]) + (wsum[2] + wsum[3]);
        inv_denom[b] = 1.0f / (t + EPS);
    }
}

// K3: out[b,c,p] = feature[b,c,p] * e_exp[b,p] * inv_denom[b]  (float4)
__global__ __launch_bounds__(256) void k_scale(
    const float* __restrict__ feature,
    const float* __restrict__ e_exp,
    const float* __restrict__ inv_denom,
    float* __restrict__ out)
{
    const int idx = blockIdx.x * 256 + threadIdx.x;   // float4 index
    const int pq = idx & (HW / 4 - 1);
    const int bc = idx >> 10;
    const int b  = bc >> 6;

    const float sc = inv_denom[b];
    const float4 e = ((const float4*)(e_exp + (size_t)b * HW))[pq];
    const float4 f = ((const float4*)feature)[idx];
    float4 o;
    o.x = f.x * (e.x * sc);
    o.y = f.y * (e.y * sc);
    o.z = f.z * (e.z * sc);
    o.w = f.w * (e.w * sc);
    ((float4*)out)[idx] = o;
}

extern "C" void kernel_launch(void* const* d_in, const int* in_sizes, int n_in,
                              void* d_out, int out_size, void* d_ws, size_t ws_size,
                              hipStream_t stream)
{
    const float* feature = (const float*)d_in[0];
    const float* query   = (const float*)d_in[1];
    const float* key     = (const float*)d_in[2];
    const float* Ua_w    = (const float*)d_in[3];
    const float* Ua_b    = (const float*)d_in[4];
    const float* Va_w    = (const float*)d_in[5];
    const float* Va_b    = (const float*)d_in[6];

    // workspace layout
    ushort_t* Whi = (ushort_t*)d_ws;                    // 512*64
    ushort_t* Wlo = Whi + NP * CH;                      // 512*64
    float* QB     = (float*)(Wlo + NP * CH);            // 32*512
    float* e_t    = QB + BSZ * NP;                      // 32*4096
    float* e_exp  = e_t + BSZ * HW;                     // 32*4096
    float* inv_denom = e_exp + BSZ * HW;                // 32

    k_prep<<<(NP * CH) / 256, 256, 0, stream>>>(Ua_w, Ua_b, query, Whi, Wlo, QB);
    k_scores<<<BSZ * (HW / 256), 256, 0, stream>>>(key, Whi, Wlo, QB, Va_w, e_t);
    k_denom<<<BSZ, 256, 0, stream>>>(e_t, Va_b, e_exp, inv_denom);
    k_scale<<<(BSZ * CH * HW / 4) / 256, 256, 0, stream>>>(feature, e_exp, inv_denom, (float*)d_out);
}